// Round 8
// baseline (327.661 us; speedup 1.0000x reference)
//
#include <hip/hip_runtime.h>
#include <hip/hip_bf16.h>

// Attention block: x[16,1024,768] -> QKV -> MHA(12 heads, d=64) -> proj.
// R8: counted-vmcnt deep prefetch AT 3 blocks/CU (the untested quadrant).
// R7 post-mortem: placement fixes exhausted (FETCH at compulsory), window
// 6633 cyc vs worst-pipe demand ~2300 -> latency-exposed staging: the
// 2-barrier loop's implicit vmcnt(0) gives ZERO prefetch distance. R2/R3's
// counted-vmcnt failed only because 128KB LDS forced 1 block/CU (TLP loss).
// Fix: BK=32, 3-deep LDS rotation (48KB -> keeps 3 blocks/CU), stage tile
// c+2 at tile c, ONE raw s_barrier per tile (wave arrival implies its
// ds_reads consumed), vmcnt ladder 8/4/0 -> ~2-tile load lead across
// barriers. LDS granule-rotation swizzle (0 conflicts), R6 XCD
// producer/consumer alignment, R7 L2 banding all kept.
// Flash attention (R5 hybrid, R6 remap) unchanged.

#define EDIM 768
#define NH 12
#define HD 64
#define BB 16
#define SN 1024
#define MTOT (BB*SN)   // 16384

typedef __attribute__((ext_vector_type(8))) short short8;
typedef __attribute__((ext_vector_type(4))) short short4v;
typedef __attribute__((ext_vector_type(4))) float f32x4;
typedef unsigned short bfr;

#if defined(__HIP_DEVICE_COMPILE__)
#if !__has_builtin(__builtin_amdgcn_mfma_f32_16x16x16bf16_1k)
#error "missing __builtin_amdgcn_mfma_f32_16x16x16bf16_1k on device"
#endif
#endif

#define MFMA32(A,B,C) __builtin_amdgcn_mfma_f32_16x16x32_bf16(A,B,C,0,0,0)
#define MFMA16(A,B,C) __builtin_amdgcn_mfma_f32_16x16x16bf16_1k(A,B,C,0,0,0)

__device__ __forceinline__ bfr f2bf(float f) {
    union { float f; unsigned int u; } v; v.f = f;
    unsigned int u = v.u;
    u += 0x7FFFu + ((u >> 16) & 1u);   // RNE
    return (bfr)(u >> 16);
}
__device__ __forceinline__ bfr f2bf_fast(float f) {
    union { float f; unsigned int u; } v; v.f = f;
    return (bfr)((v.u + 0x8000u) >> 16);
}

// async global->LDS, 16 bytes per lane; lds base must be wave-uniform.
__device__ __forceinline__ void gl2lds16(const bfr* g, bfr* l) {
    __builtin_amdgcn_global_load_lds(
        (__attribute__((address_space(1))) void*)(g),
        (__attribute__((address_space(3))) void*)(l), 16, 0, 0);
}

#define BAR()   __builtin_amdgcn_s_barrier()
#define VMC(n)  asm volatile("s_waitcnt vmcnt(" #n ")" ::: "memory")

// ---------------- convert fp32 -> bf16 ----------------
// Block remap: hardware XCD = blockIdx%8; XCD x processes contiguous chunk
// band [x*1536, (x+1)*1536) -> rows [2048x, 2048x+2048) of the 16384-row x.
__global__ void k_convert(const float* __restrict__ in, bfr* __restrict__ out, int n4) {
    const int j = (blockIdx.x & 7) * 1536 + (blockIdx.x >> 3);   // 12288 blocks
    int i = j * blockDim.x + threadIdx.x;
    if (i >= n4) return;
    float4 v = ((const float4*)in)[i];
    ushort4 o;
    o.x = f2bf(v.x); o.y = f2bf(v.y); o.z = f2bf(v.z); o.w = f2bf(v.w);
    ((ushort4*)out)[i] = o;
}

// ---------------- transpose + convert: in[R][C] fp32 -> out[C][R] bf16 ----------------
__global__ void k_transpose_bf16(const float* __restrict__ in, bfr* __restrict__ out,
                                 int R, int C) {
    __shared__ float tile[32][33];
    int c0 = blockIdx.x * 32, r0 = blockIdx.y * 32;
    int tx = threadIdx.x & 31, ty = threadIdx.x >> 5;
    #pragma unroll
    for (int i = 0; i < 32; i += 8)
        tile[ty + i][tx] = in[(size_t)(r0 + ty + i) * C + c0 + tx];
    __syncthreads();
    #pragma unroll
    for (int i = 0; i < 32; i += 8)
        out[(size_t)(c0 + ty + i) * R + r0 + tx] = f2bf(tile[tx][ty + i]);
}

// ---------------- bf16 MFMA GEMM: C[M,N] = A[M,768] @ BT[N,768]^T + bias ----------------
// BK=32 per tile, NT=24 tiles. 3-deep LDS rotation: read buf rb=c%3, stage
// buf (c+2)%3 at tile c. Per tile: {BAR | stage c+2 (4 gl2lds) | vmcnt ladder
// | ds_read a,b | 16 MFMA}. Safety: wave arrival at BAR implies its MFMAs
// issued implies all its ds_reads of buf[(c+2)%3] (tile c-1) completed, so
// post-barrier staging cannot race them. vmcnt(8) after issuing c+2 leaves
// tiles c+1,c+2 (8 loads/wave) in flight; guarantees tile c landed.
// Slab layout [row][32], granule-rotated: phys = (logical + (row>>1)) & 3.
// Block remap (R7): xcd=wgid&7 owns m-tiles [16x,16x+16), 2 bands of 8,
// n-major within band -> A-band pinned in local L2.
#define QSCALE 0.18033688011112042f   // log2(e)/8
#define NT 24

template <int EPI>
__launch_bounds__(256, 3)
__global__ void k_gemm_bt(const bfr* __restrict__ A, const bfr* __restrict__ BT,
                          const float* __restrict__ bias, float* __restrict__ out,
                          bfr* __restrict__ qb, bfr* __restrict__ kb, bfr* __restrict__ vT) {
    __shared__ bfr As[3][128 * 32];   // [buf][row*32 + col]
    __shared__ bfr Bs[3][128 * 32];

    const int wgid = blockIdx.y * gridDim.x + blockIdx.x;
    const int xcd = wgid & 7;
    const int idx = wgid >> 3;
    const int half = gridDim.x << 3;           // 8 * gx
    const int band = idx / half;               // 0 or 1
    const int r = idx - band * half;
    const int n0 = (r >> 3) * 128;
    const int m0 = (xcd * 16 + band * 8 + (r & 7)) * 128;

    const int t = threadIdx.x;
    const int lane = t & 63;
    const int wave = t >> 6;
    const int wr = wave >> 1, wc = wave & 1;
    const int l15 = lane & 15, quad = lane >> 4;

    f32x4 acc[4][4] = {};

    // staging map (per instruction): thread t's 16B lands at LDS elems [t*8,t*8+8):
    // row = t>>2, phys granule = t&3, logical (global) granule = (phys - (row>>1)) & 3.
    const int srow = t >> 2;
    const int sg = ((t & 3) - (t >> 3)) & 3;
    const bfr* gA0 = A  + (size_t)(m0 + srow) * 768 + sg * 8;
    const bfr* gA1 = A  + (size_t)(m0 + 64 + srow) * 768 + sg * 8;
    const bfr* gB0 = BT + (size_t)(n0 + srow) * 768 + sg * 8;
    const bfr* gB1 = BT + (size_t)(n0 + 64 + srow) * 768 + sg * 8;
    const int w512 = wave * 512;

    // read-side: phys granule = (quad + (row>>1)) & 3; row bases are 0 mod 16
    // so (row>>1)&3 == (l15>>1)&3.
    const int pg = ((quad + (l15 >> 1)) & 3) * 8;
    const int arow = (wr * 64 + l15) * 32;   // + rt*512
    const int brow = (wc * 64 + l15) * 32;   // + ct*512

#define STG(buf, kk) { gl2lds16(gA0 + (kk), &As[buf][w512]); \
                       gl2lds16(gA1 + (kk), &As[buf][2048 + w512]); \
                       gl2lds16(gB0 + (kk), &Bs[buf][w512]); \
                       gl2lds16(gB1 + (kk), &Bs[buf][2048 + w512]); }

    // prologue: tiles 0,1 staged into bufs 0,1 (8 loads/wave in flight)
    STG(0, 0);
    STG(1, 32);

    int rb = 0;
    for (int c = 0; c < NT; ++c) {
        BAR();   // all waves finished tile c-1's ds_reads of buf (c+2)%3
        const int sb = (rb + 2 >= 3) ? rb - 1 : rb + 2;
        if (c < NT - 2) STG(sb, (c + 2) * 32);
        if (c < NT - 2)       { VMC(8); }   // tile c landed; c+1,c+2 in flight
        else if (c == NT - 2) { VMC(4); }   // tile c landed; c+1 in flight
        else                  { VMC(0); }   // last tile landed

        short8 af[4], bf[4];
        const bfr* Ap = &As[rb][0];
        const bfr* Bp = &Bs[rb][0];
        #pragma unroll
        for (int rt = 0; rt < 4; rt++)
            af[rt] = *(const short8*)(Ap + arow + rt * 512 + pg);
        #pragma unroll
        for (int ct = 0; ct < 4; ct++)
            bf[ct] = *(const short8*)(Bp + brow + ct * 512 + pg);

        __builtin_amdgcn_s_setprio(1);
        #pragma unroll
        for (int rt = 0; rt < 4; rt++)
            #pragma unroll
            for (int ct = 0; ct < 4; ct++)
                acc[rt][ct] = MFMA32(af[rt], bf[ct], acc[rt][ct]);
        __builtin_amdgcn_s_setprio(0);

        rb = (rb == 2) ? 0 : rb + 1;
    }

    #pragma unroll
    for (int rt = 0; rt < 4; rt++) {
        #pragma unroll
        for (int ct = 0; ct < 4; ct++) {
            const int col = n0 + wc * 64 + ct * 16 + l15;
            const float bv = bias[col];
            #pragma unroll
            for (int reg = 0; reg < 4; reg++) {
                const int m = m0 + wr * 64 + rt * 16 + quad * 4 + reg;
                float val = acc[rt][ct][reg] + bv;
                if constexpr (EPI == 0) {
                    out[(size_t)m * EDIM + col] = val;
                } else {
                    const int three = col / 768;
                    const int rem = col - three * 768;
                    const int h = rem >> 6, d = rem & 63;
                    const int b = m >> 10, n = m & 1023;
                    const size_t bh = (size_t)b * NH + h;
                    if (three == 0)      qb[(bh * SN + n) * HD + d] = f2bf(val * QSCALE);
                    else if (three == 1) kb[(bh * SN + n) * HD + d] = f2bf(val);
                    else                 vT[(bh * HD + d) * SN + n] = f2bf(val);
                }
            }
        }
    }
}

// ---------------- flash attention (R5): LDS-staged K/V, register-resident P ----------------
#define LDK 72   // 144B row stride = 9 x 16B: aligned b128, conflict-light

__launch_bounds__(256, 2)
__global__ void k_attn(const bfr* __restrict__ qb, const bfr* __restrict__ kb,
                       const bfr* __restrict__ vT, bfr* __restrict__ ao) {
    __shared__ bfr Ks[2][64 * LDK];
    __shared__ bfr Vs[2][64 * LDK];

    // XCD-aligned remap: grid (192,8) -> 1536 blocks; XCD x handles
    // bh in [24x,24x+24) (batches 2x,2x+1), matching QKV-epilogue writes
    // and proj's ao reads. Bijective: idx%24 + 24*xcd, q0 = (idx/24)*128.
    const int linear = blockIdx.y * gridDim.x + blockIdx.x;
    const int idx = linear >> 3;
    const int bh = (linear & 7) * 24 + idx % 24;
    const int q0 = (idx / 24) * 128;

    const int t = threadIdx.x;
    const int lane = t & 63, w = t >> 6;
    const int l15 = lane & 15, quad = lane >> 4;

    const bfr* qbase = qb + (size_t)bh * SN * HD;
    const bfr* kbase = kb + (size_t)bh * SN * HD;
    const bfr* vbase = vT + (size_t)bh * HD * SN;

    short8 qf[2][2];
    #pragma unroll
    for (int qt = 0; qt < 2; qt++)
        #pragma unroll
        for (int c = 0; c < 2; c++)
            qf[qt][c] = *(const short8*)(qbase + (size_t)(q0 + w * 32 + qt * 16 + l15) * HD + c * 32 + quad * 8);

    f32x4 o_acc[2][4] = {};
    f32x4 l_acc[2] = {};
    short4v ones4;
    #pragma unroll
    for (int i = 0; i < 4; i++) ones4[i] = (short)0x3F80;

    const int srow = t >> 2;
    const int scol = (t & 3) * 16;
    const bfr* gK = kbase + (size_t)srow * HD + scol;
    const bfr* gV = vbase + (size_t)srow * SN + scol;
    const int soff = srow * LDK + scol;

    uint4 kr0, kr1, vr0, vr1;
    kr0 = *(const uint4*)(gK);      kr1 = *(const uint4*)(gK + 8);
    vr0 = *(const uint4*)(gV);      vr1 = *(const uint4*)(gV + 8);
    *(uint4*)(&Ks[0][soff]) = kr0;  *(uint4*)(&Ks[0][soff + 8]) = kr1;
    *(uint4*)(&Vs[0][soff]) = vr0;  *(uint4*)(&Vs[0][soff + 8]) = vr1;

    for (int it = 0; it < SN / 64; it++) {
        const int cur = it & 1;
        const int kv0n = (it + 1) * 64;
        if (kv0n < SN) {
            kr0 = *(const uint4*)(gK + (size_t)kv0n * HD);
            kr1 = *(const uint4*)(gK + (size_t)kv0n * HD + 8);
            vr0 = *(const uint4*)(gV + kv0n);
            vr1 = *(const uint4*)(gV + kv0n + 8);
        }
        __syncthreads();
        if (kv0n < SN) {
            *(uint4*)(&Ks[cur ^ 1][soff]) = kr0;  *(uint4*)(&Ks[cur ^ 1][soff + 8]) = kr1;
            *(uint4*)(&Vs[cur ^ 1][soff]) = vr0;  *(uint4*)(&Vs[cur ^ 1][soff + 8]) = vr1;
        }

        const bfr* Kc = &Ks[cur][0];
        const bfr* Vc = &Vs[cur][0];

        short8 kf[4][2];
        #pragma unroll
        for (int kvt = 0; kvt < 4; kvt++)
            #pragma unroll
            for (int c = 0; c < 2; c++)
                kf[kvt][c] = *(const short8*)(Kc + (kvt * 16 + l15) * LDK + c * 32 + quad * 8);
        short4v vf[4][4];
        #pragma unroll
        for (int kvt = 0; kvt < 4; kvt++)
            #pragma unroll
            for (int ct = 0; ct < 4; ct++)
                vf[kvt][ct] = *(const short4v*)(Vc + (ct * 16 + l15) * LDK + kvt * 16 + quad * 4);

        f32x4 st[4][2] = {};
        #pragma unroll
        for (int c = 0; c < 2; c++)
            #pragma unroll
            for (int kvt = 0; kvt < 4; kvt++)
                #pragma unroll
                for (int qt = 0; qt < 2; qt++)
                    st[kvt][qt] = MFMA32(kf[kvt][c], qf[qt][c], st[kvt][qt]);

        short4v pf[4][2];
        #pragma unroll
        for (int kvt = 0; kvt < 4; kvt++)
            #pragma unroll
            for (int qt = 0; qt < 2; qt++) {
                union { unsigned u[2]; short4v s; } cv;
                cv.u[0] = (unsigned)f2bf_fast(exp2f(st[kvt][qt][0]))
                        | ((unsigned)f2bf_fast(exp2f(st[kvt][qt][1])) << 16);
                cv.u[1] = (unsigned)f2bf_fast(exp2f(st[kvt][qt][2]))
                        | ((unsigned)f2bf_fast(exp2f(st[kvt][qt][3])) << 16);
                pf[kvt][qt] = cv.s;
            }

        #pragma unroll
        for (int kvt = 0; kvt < 4; kvt++)
            #pragma unroll
            for (int qt = 0; qt < 2; qt++)
                l_acc[qt] = MFMA16(pf[kvt][qt], ones4, l_acc[qt]);
        #pragma unroll
        for (int kvt = 0; kvt < 4; kvt++)
            #pragma unroll
            for (int qt = 0; qt < 2; qt++)
                #pragma unroll
                for (int ct = 0; ct < 4; ct++)
                    o_acc[qt][ct] = MFMA16(pf[kvt][qt], vf[kvt][ct], o_acc[qt][ct]);
    }

    const int bb = bh / NH, h = bh % NH;
    #pragma unroll
    for (int qt = 0; qt < 2; qt++) {
        #pragma unroll
        for (int r = 0; r < 4; r++) {
            const float inv = 1.0f / l_acc[qt][r];
            const int n = q0 + w * 32 + qt * 16 + quad * 4 + r;
            #pragma unroll
            for (int ct = 0; ct < 4; ct++) {
                const int d = ct * 16 + l15;
                ao[((size_t)bb * SN + n) * EDIM + h * HD + d] = f2bf_fast(o_acc[qt][ct][r] * inv);
            }
        }
    }
}

extern "C" void kernel_launch(void* const* d_in, const int* in_sizes, int n_in,
                              void* d_out, int out_size, void* d_ws, size_t ws_size,
                              hipStream_t stream) {
    const float* x      = (const float*)d_in[0];
    const float* w_qkv  = (const float*)d_in[1];
    const float* b_qkv  = (const float*)d_in[2];
    const float* w_proj = (const float*)d_in[3];
    const float* b_proj = (const float*)d_in[4];

    char* ws = (char*)d_ws;
    bfr* xb     = (bfr*)(ws + 0);
    bfr* wqkvT  = (bfr*)(ws + 25165824);
    bfr* wprojT = (bfr*)(ws + 28704768);
    bfr* qb     = (bfr*)(ws + 29884416);
    bfr* kb     = (bfr*)(ws + 55050240);
    bfr* vT     = (bfr*)(ws + 80216064);
    bfr* ao     = (bfr*)(ws + 105381888);

    k_convert<<<12288, 256, 0, stream>>>(x, xb, (MTOT * EDIM) / 4);
    k_transpose_bf16<<<dim3(2304 / 32, 768 / 32), 256, 0, stream>>>(w_qkv, wqkvT, 768, 2304);
    k_transpose_bf16<<<dim3(768 / 32, 768 / 32), 256, 0, stream>>>(w_proj, wprojT, 768, 768);
    k_gemm_bt<1><<<dim3(2304 / 128, MTOT / 128), 256, 0, stream>>>(
        xb, wqkvT, b_qkv, nullptr, qb, kb, vT);
    k_attn<<<dim3(BB * NH, SN / 128), 256, 0, stream>>>(qb, kb, vT, ao);
    k_gemm_bt<0><<<dim3(768 / 128, MTOT / 128), 256, 0, stream>>>(
        ao, wprojT, b_proj, (float*)d_out, nullptr, nullptr, nullptr);
}